// Round 1
// baseline (1307.579 us; speedup 1.0000x reference)
//
#include <hip/hip_runtime.h>
#include <hip/hip_bf16.h>
#include <stdint.h>

#define Bb 4
#define Ss 8192
#define Hh 2048
#define NHh 16
#define DHh 128
#define DFFf 8192
#define KS 1024
#define NTOK 4096

typedef unsigned short u16;
typedef __bf16 bf16x8 __attribute__((ext_vector_type(8)));
typedef float f32x4 __attribute__((ext_vector_type(4)));

union B8 { uint4 u; bf16x8 v; u16 s[8]; };

__device__ __forceinline__ float b2f(u16 x) { return __uint_as_float(((unsigned)x) << 16); }
__device__ __forceinline__ u16 f2b(float x) {
  __hip_bfloat16 h = __float2bfloat16(x);
  return *reinterpret_cast<u16*>(&h);
}

__device__ __forceinline__ void gll16(const void* g, void* l) {
  __builtin_amdgcn_global_load_lds((const __attribute__((address_space(1))) void*)g,
                                   (__attribute__((address_space(3))) void*)l, 16, 0, 0);
}

// ---------------- top-k index scan (stable first-K true positions) ----------------
__global__ void topk_prep(const void* maskp, const int* __restrict__ posids,
                          const float* __restrict__ scores,
                          int* __restrict__ idx, int* __restrict__ posg,
                          float* __restrict__ scalev) {
  int b = blockIdx.x;
  int tid = threadIdx.x, lane = tid & 63, wv = tid >> 6;
  __shared__ int wsum[4];
  __shared__ int base;
  __shared__ int mode;
  __shared__ int detCnt;
  if (tid == 0) { base = 0; detCnt = 0; }
  __syncthreads();
  {
    const unsigned char* mb = (const unsigned char*)maskp;
    int c = 0;
    for (int s = tid; s < 8192; s += 256) c += (mb[s] != 0);
    atomicAdd(&detCnt, c);
  }
  __syncthreads();
  if (tid == 0) mode = (detCnt == KS) ? 1 : 0;  // 1 = byte-encoded mask
  __syncthreads();
  const unsigned char* mb = (const unsigned char*)maskp;
  const int* mi = (const int*)maskp;
  for (int s0 = 0; s0 < Ss; s0 += 256) {
    int s = s0 + tid;
    int pred = mode ? (mb[(size_t)b * Ss + s] != 0) : (mi[(size_t)b * Ss + s] != 0);
    unsigned long long bal = __ballot(pred);
    int lp = __popcll(bal & ((1ull << lane) - 1ull));
    int wtot = __popcll(bal);
    if (lane == 0) wsum[wv] = wtot;
    __syncthreads();
    int woff = 0;
    for (int w = 0; w < wv; ++w) woff += wsum[w];
    int tot = wsum[0] + wsum[1] + wsum[2] + wsum[3];
    int p = base + woff + lp;
    if (pred && p < KS) {
      idx[b * KS + p] = s;
      posg[b * KS + p] = posids[(size_t)b * Ss + s];
    }
    __syncthreads();
    if (tid == 0) base += tot;
    __syncthreads();
  }
  if (b == 0 && tid < Bb) scalev[tid] = 0.5f * 1.0f + (scores[tid] - 0.5f) * 1.0f;
}

// ---------------- weight transpose fp32 -> bf16 (out[C][R] = in[R][C]) ----------------
__global__ void transpose_w(const float* __restrict__ in, u16* __restrict__ out, int R, int C) {
  __shared__ float tile[32][33];
  int tx = threadIdx.x, ty = threadIdx.y;
  int c0 = blockIdx.x * 32, r0 = blockIdx.y * 32;
  for (int j = ty; j < 32; j += 8) tile[j][tx] = in[(size_t)(r0 + j) * C + c0 + tx];
  __syncthreads();
  for (int j = ty; j < 32; j += 8) out[(size_t)(c0 + j) * R + r0 + tx] = f2b(tile[tx][j]);
}

// ---------------- RMSNorm (optionally gathering rows of hidden) ----------------
template <int GATHER>
__global__ __launch_bounds__(256) void rmsnorm_k(const float* __restrict__ src0,
                                                 const int* __restrict__ idx,
                                                 const float* __restrict__ w,
                                                 u16* __restrict__ out) {
  int t = blockIdx.x;
  const float* src;
  if (GATHER) { int b = t >> 10; src = src0 + ((size_t)b * Ss + idx[t]) * Hh; }
  else src = src0 + (size_t)t * Hh;
  int tid = threadIdx.x, lane = tid & 63, wv = tid >> 6;
  float4 x0 = *(const float4*)(src + tid * 8);
  float4 x1 = *(const float4*)(src + tid * 8 + 4);
  float ss = x0.x * x0.x + x0.y * x0.y + x0.z * x0.z + x0.w * x0.w +
             x1.x * x1.x + x1.y * x1.y + x1.z * x1.z + x1.w * x1.w;
  for (int o = 32; o; o >>= 1) ss += __shfl_down(ss, o);
  __shared__ float wred[4];
  if (lane == 0) wred[wv] = ss;
  __syncthreads();
  float tot = wred[0] + wred[1] + wred[2] + wred[3];
  float r = rsqrtf(tot * (1.0f / Hh) + 1e-5f);
  const float* wp = w + tid * 8;
  u16* op = out + (size_t)t * Hh + tid * 8;
  float xs[8] = {x0.x, x0.y, x0.z, x0.w, x1.x, x1.y, x1.z, x1.w};
#pragma unroll
  for (int j = 0; j < 8; ++j) op[j] = f2b(xs[j] * r * wp[j]);
}

// ---------------- 128x128 bf16 GEMM, B^T input, templated epilogue ----------------
// EPI 0: C_bf16[row*N+col] = acc
// EPI 1: hs2_f32[row*H+col] = hidden[b][idx[row]][col] + acc
// EPI 2: out_f32[b][idx[row]][col] = hs2[row*H+col] + acc*scale[b]
template <int EPI>
__global__ __launch_bounds__(256) void gemm_bt(const u16* __restrict__ A,
                                               const u16* __restrict__ Bt, int N, int Kd,
                                               u16* __restrict__ Cb,
                                               const float* __restrict__ hid,
                                               const int* __restrict__ idx,
                                               const float* __restrict__ hs2,
                                               const float* __restrict__ scalev,
                                               float* __restrict__ Cf) {
  __shared__ u16 As[128 * 32];
  __shared__ u16 Bs[128 * 32];
  int m0 = blockIdx.x * 128, n0 = blockIdx.y * 128;
  int tid = threadIdx.x, lane = tid & 63, wv = tid >> 6;
  int wm = wv >> 1, wn = wv & 1;
  f32x4 acc[4][4] = {};
  for (int k0 = 0; k0 < Kd; k0 += 32) {
    __syncthreads();
    for (int c = wv; c < 8; c += 4) {
      gll16(A + (size_t)(m0 + c * 16 + (lane >> 2)) * Kd + k0 + (lane & 3) * 8, &As[c * 512]);
      gll16(Bt + (size_t)(n0 + c * 16 + (lane >> 2)) * Kd + k0 + (lane & 3) * 8, &Bs[c * 512]);
    }
    __syncthreads();
    B8 a[4], bb[4];
#pragma unroll
    for (int m = 0; m < 4; ++m)
      a[m].u = *(const uint4*)&As[(wm * 64 + m * 16 + (lane & 15)) * 32 + (lane >> 4) * 8];
#pragma unroll
    for (int n = 0; n < 4; ++n)
      bb[n].u = *(const uint4*)&Bs[(wn * 64 + n * 16 + (lane & 15)) * 32 + (lane >> 4) * 8];
#pragma unroll
    for (int m = 0; m < 4; ++m)
#pragma unroll
      for (int n = 0; n < 4; ++n)
        acc[m][n] = __builtin_amdgcn_mfma_f32_16x16x32_bf16(a[m].v, bb[n].v, acc[m][n], 0, 0, 0);
  }
#pragma unroll
  for (int m = 0; m < 4; ++m) {
#pragma unroll
    for (int r = 0; r < 4; ++r) {
      int row = m0 + wm * 64 + m * 16 + (lane >> 4) * 4 + r;
#pragma unroll
      for (int n = 0; n < 4; ++n) {
        int col = n0 + wn * 64 + n * 16 + (lane & 15);
        float v = acc[m][n][r];
        if (EPI == 0) {
          Cb[(size_t)row * N + col] = f2b(v);
        } else if (EPI == 1) {
          int b = row >> 10;
          Cf[(size_t)row * Hh + col] = hid[((size_t)b * Ss + idx[row]) * Hh + col] + v;
        } else {
          int b = row >> 10;
          Cf[((size_t)b * Ss + idx[row]) * Hh + col] = hs2[(size_t)row * Hh + col] + v * scalev[b];
        }
      }
    }
  }
}

// ---------------- RoPE on Q and K (in place, gathered positions) ----------------
__global__ __launch_bounds__(256) void rope_qk(u16* __restrict__ Q, u16* __restrict__ Kq,
                                               const int* __restrict__ posg) {
  int gid = blockIdx.x * 256 + threadIdx.x;  // NTOK*NH*64
  int i = gid & 63;
  int h = (gid >> 6) & 15;
  int t = gid >> 10;
  float p = (float)posg[t];
  float inv = exp2f(-(float)i * (13.287712379549449f / 64.0f));  // 10000^(-i/64)
  float ang = p * inv;
  float sv, cv;
  sincosf(ang, &sv, &cv);
  size_t base = (size_t)t * Hh + h * DHh + i;
  float q1 = b2f(Q[base]), q2 = b2f(Q[base + 64]);
  Q[base] = f2b(q1 * cv - q2 * sv);
  Q[base + 64] = f2b(q2 * cv + q1 * sv);
  float k1 = b2f(Kq[base]), k2 = b2f(Kq[base + 64]);
  Kq[base] = f2b(k1 * cv - k2 * sv);
  Kq[base + 64] = f2b(k2 * cv + k1 * sv);
}

// ---------------- flash attention: S^T = mfma(K,Q), online softmax, PV via LDS bounce ----------------
__global__ __launch_bounds__(256) void attn_k(const u16* __restrict__ Q, const u16* __restrict__ Kk,
                                              const u16* __restrict__ V, u16* __restrict__ O) {
  int qb = blockIdx.x;    // 16 q-tiles of 64
  int head = blockIdx.y;  // 64 = b*16+h
  int b = head >> 4, h = head & 15;
  int tid = threadIdx.x, lane = tid & 63, wv = tid >> 6;
  __shared__ __align__(16) u16 Ks[32][136];
  __shared__ __align__(16) u16 Vs[128][40];
  __shared__ __align__(16) u16 Ps[4][16][40];
  int q0 = qb * 64 + wv * 16;
  int tokQ = b * KS + q0;
  B8 qf[4];
  const u16* qp = Q + (size_t)(tokQ + (lane & 15)) * Hh + h * DHh;
#pragma unroll
  for (int c = 0; c < 4; ++c) qf[c].u = *(const uint4*)(qp + c * 32 + (lane >> 4) * 8);
  float m_run = -1e30f, l_run = 0.0f;
  f32x4 oacc[8] = {};
  int kmax = qb * 64 + 64;
  for (int ks = 0; ks < kmax; ks += 32) {
    __syncthreads();
    for (int s = tid; s < 512; s += 256) {
      int key = s >> 4, d0 = (s & 15) * 8;
      size_t gb = (size_t)(b * KS + ks + key) * Hh + h * DHh + d0;
      uint4 kv = *(const uint4*)(Kk + gb);
      *(uint4*)&Ks[key][d0] = kv;
      uint4 vv = *(const uint4*)(V + gb);
      u16* vp = (u16*)&vv;
      int kb = key >> 3, ko = key & 7;
#pragma unroll
      for (int j = 0; j < 8; ++j) {
        int d = d0 + j;
        Vs[d][((kb ^ ((d >> 3) & 3)) << 3) | ko] = vp[j];
      }
    }
    __syncthreads();
    f32x4 st[2] = {};
#pragma unroll
    for (int c = 0; c < 4; ++c) {
      B8 k0f, k1f;
      k0f.u = *(const uint4*)&Ks[lane & 15][c * 32 + (lane >> 4) * 8];
      k1f.u = *(const uint4*)&Ks[16 + (lane & 15)][c * 32 + (lane >> 4) * 8];
      st[0] = __builtin_amdgcn_mfma_f32_16x16x32_bf16(k0f.v, qf[c].v, st[0], 0, 0, 0);
      st[1] = __builtin_amdgcn_mfma_f32_16x16x32_bf16(k1f.v, qf[c].v, st[1], 0, 0, 0);
    }
    int qi = q0 + (lane & 15);
    float pmax = -INFINITY;
#pragma unroll
    for (int kt = 0; kt < 2; ++kt)
#pragma unroll
      for (int r = 0; r < 4; ++r) {
        int ki = ks + kt * 16 + (lane >> 4) * 4 + r;
        float v = st[kt][r] * 0.088388347648318447f;
        v = (ki <= qi) ? v : -INFINITY;
        st[kt][r] = v;
        pmax = fmaxf(pmax, v);
      }
    pmax = fmaxf(pmax, __shfl_xor(pmax, 16));
    pmax = fmaxf(pmax, __shfl_xor(pmax, 32));
    float m_new = fmaxf(m_run, pmax);
    float alpha = __expf(m_run - m_new);
    float psum = 0.0f;
#pragma unroll
    for (int kt = 0; kt < 2; ++kt)
#pragma unroll
      for (int r = 0; r < 4; ++r) {
        float pv = __expf(st[kt][r] - m_new);
        st[kt][r] = pv;
        psum += pv;
      }
    psum += __shfl_xor(psum, 16);
    psum += __shfl_xor(psum, 32);
    l_run = l_run * alpha + psum;
    m_run = m_new;
#pragma unroll
    for (int kt = 0; kt < 2; ++kt) {
      ushort4 pk;
      pk.x = f2b(st[kt][0]); pk.y = f2b(st[kt][1]);
      pk.z = f2b(st[kt][2]); pk.w = f2b(st[kt][3]);
      *(ushort4*)&Ps[wv][lane & 15][kt * 16 + (lane >> 4) * 4] = pk;
    }
    B8 pf;
    pf.u = *(const uint4*)&Ps[wv][lane & 15][(lane >> 4) * 8];
    float al0 = __shfl(alpha, (lane >> 4) * 4 + 0);
    float al1 = __shfl(alpha, (lane >> 4) * 4 + 1);
    float al2 = __shfl(alpha, (lane >> 4) * 4 + 2);
    float al3 = __shfl(alpha, (lane >> 4) * 4 + 3);
#pragma unroll
    for (int dt = 0; dt < 8; ++dt) {
      oacc[dt][0] *= al0; oacc[dt][1] *= al1;
      oacc[dt][2] *= al2; oacc[dt][3] *= al3;
    }
#pragma unroll
    for (int dt = 0; dt < 8; ++dt) {
      int d = dt * 16 + (lane & 15);
      B8 vf;
      vf.u = *(const uint4*)&Vs[d][(((lane >> 4) ^ ((d >> 3) & 3)) << 3)];
      oacc[dt] = __builtin_amdgcn_mfma_f32_16x16x32_bf16(pf.v, vf.v, oacc[dt], 0, 0, 0);
    }
  }
  float linv = 1.0f / l_run;
  float li[4];
#pragma unroll
  for (int r = 0; r < 4; ++r) li[r] = __shfl(linv, (lane >> 4) * 4 + r);
#pragma unroll
  for (int r = 0; r < 4; ++r) {
    int tok = tokQ + (lane >> 4) * 4 + r;
    u16* op = O + (size_t)tok * Hh + h * DHh;
#pragma unroll
    for (int dt = 0; dt < 8; ++dt) op[dt * 16 + (lane & 15)] = f2b(oacc[dt][r] * li[r]);
  }
}

// ---------------- silu(g)*u, in place into g ----------------
__global__ __launch_bounds__(256) void silu_mul(u16* __restrict__ g, const u16* __restrict__ u) {
  size_t i0 = ((size_t)blockIdx.x * 256 + threadIdx.x) * 8;
  B8 gv, uv;
  gv.u = *(const uint4*)(g + i0);
  uv.u = *(const uint4*)(u + i0);
#pragma unroll
  for (int j = 0; j < 8; ++j) {
    float x = b2f(gv.s[j]), y = b2f(uv.s[j]);
    gv.s[j] = f2b(x / (1.0f + __expf(-x)) * y);
  }
  *(uint4*)(g + i0) = gv.u;
}

extern "C" void kernel_launch(void* const* d_in, const int* in_sizes, int n_in,
                              void* d_out, int out_size, void* d_ws, size_t ws_size,
                              hipStream_t stream) {
  (void)in_sizes; (void)n_in; (void)out_size; (void)ws_size;
  const float* hid = (const float*)d_in[0];
  const int* posids = (const int*)d_in[1];
  const void* mask = d_in[2];
  const float* scores = (const float*)d_in[3];
  const float* Wq = (const float*)d_in[5];
  const float* Wk = (const float*)d_in[6];
  const float* Wv = (const float*)d_in[7];
  const float* Wo = (const float*)d_in[8];
  const float* Wg = (const float*)d_in[9];
  const float* Wu = (const float*)d_in[10];
  const float* Wd = (const float*)d_in[11];
  const float* ln1 = (const float*)d_in[12];
  const float* ln2 = (const float*)d_in[13];
  float* out = (float*)d_out;
  char* ws = (char*)d_ws;

  u16* WqT = (u16*)(ws + 0);
  u16* WkT = (u16*)(ws + 8388608);
  u16* WvT = (u16*)(ws + 16777216);
  u16* WoT = (u16*)(ws + 25165824);
  u16* WgT = (u16*)(ws + 33554432);
  u16* WuT = (u16*)(ws + 67108864);
  u16* WdT = (u16*)(ws + 100663296);
  int* idx = (int*)(ws + 134217728);
  int* posg = (int*)(ws + 134217728 + 16384);
  float* scalev = (float*)(ws + 134217728 + 32768);
  char* pool = ws + 134283264;  // 128 MiB pool, reused across phases
  u16* hsn = (u16*)(pool);
  u16* Qb = (u16*)(pool + 16777216);
  u16* Kb = (u16*)(pool + 33554432);
  u16* Vb = (u16*)(pool + 50331648);
  u16* attn_o = (u16*)(pool + 67108864);
  u16* gbuf = (u16*)(pool);              // overlays hsn/Qb/Kb/Vb (dead by then)
  u16* ubuf = (u16*)(pool + 67108864);   // overlays attn_o (dead by then)
  float* hs2 = (float*)(ws + 268500992);
  u16* mnorm = (u16*)(ws + 302055424);

  // out = hidden (non-selected rows pass through; selected rows overwritten later)
  hipMemcpyAsync(out, hid, (size_t)Bb * Ss * Hh * 4, hipMemcpyDeviceToDevice, stream);

  topk_prep<<<Bb, 256, 0, stream>>>(mask, posids, scores, idx, posg, scalev);

  transpose_w<<<dim3(64, 64), dim3(32, 8), 0, stream>>>(Wq, WqT, 2048, 2048);
  transpose_w<<<dim3(64, 64), dim3(32, 8), 0, stream>>>(Wk, WkT, 2048, 2048);
  transpose_w<<<dim3(64, 64), dim3(32, 8), 0, stream>>>(Wv, WvT, 2048, 2048);
  transpose_w<<<dim3(64, 64), dim3(32, 8), 0, stream>>>(Wo, WoT, 2048, 2048);
  transpose_w<<<dim3(256, 64), dim3(32, 8), 0, stream>>>(Wg, WgT, 2048, 8192);
  transpose_w<<<dim3(256, 64), dim3(32, 8), 0, stream>>>(Wu, WuT, 2048, 8192);
  transpose_w<<<dim3(64, 256), dim3(32, 8), 0, stream>>>(Wd, WdT, 8192, 2048);

  rmsnorm_k<1><<<NTOK, 256, 0, stream>>>(hid, idx, ln1, hsn);

  dim3 g16(32, 16), g64(32, 64);
  gemm_bt<0><<<g16, 256, 0, stream>>>(hsn, WqT, 2048, 2048, Qb, nullptr, nullptr, nullptr, nullptr, nullptr);
  gemm_bt<0><<<g16, 256, 0, stream>>>(hsn, WkT, 2048, 2048, Kb, nullptr, nullptr, nullptr, nullptr, nullptr);
  gemm_bt<0><<<g16, 256, 0, stream>>>(hsn, WvT, 2048, 2048, Vb, nullptr, nullptr, nullptr, nullptr, nullptr);

  rope_qk<<<16384, 256, 0, stream>>>(Qb, Kb, posg);

  attn_k<<<dim3(16, 64), 256, 0, stream>>>(Qb, Kb, Vb, attn_o);

  gemm_bt<1><<<g16, 256, 0, stream>>>(attn_o, WoT, 2048, 2048, nullptr, hid, idx, nullptr, nullptr, hs2);

  rmsnorm_k<0><<<NTOK, 256, 0, stream>>>(hs2, nullptr, ln2, mnorm);

  gemm_bt<0><<<g64, 256, 0, stream>>>(mnorm, WgT, 8192, 2048, gbuf, nullptr, nullptr, nullptr, nullptr, nullptr);
  gemm_bt<0><<<g64, 256, 0, stream>>>(mnorm, WuT, 8192, 2048, ubuf, nullptr, nullptr, nullptr, nullptr, nullptr);

  silu_mul<<<16384, 256, 0, stream>>>(gbuf, ubuf);

  gemm_bt<2><<<g16, 256, 0, stream>>>(gbuf, WdT, 2048, 8192, nullptr, nullptr, idx, hs2, scalev, out);
}

// Round 2
// 1282.202 us; speedup vs baseline: 1.0198x; 1.0198x over previous
//
#include <hip/hip_runtime.h>
#include <hip/hip_bf16.h>
#include <stdint.h>

#define Bb 4
#define Ss 8192
#define Hh 2048
#define NHh 16
#define DHh 128
#define DFFf 8192
#define KS 1024
#define NTOK 4096

typedef unsigned short u16;
typedef __bf16 bf16x8 __attribute__((ext_vector_type(8)));
typedef float f32x4 __attribute__((ext_vector_type(4)));

union B8 { uint4 u; bf16x8 v; u16 s[8]; };

__device__ __forceinline__ float b2f(u16 x) { return __uint_as_float(((unsigned)x) << 16); }
__device__ __forceinline__ u16 f2b(float x) {
  __hip_bfloat16 h = __float2bfloat16(x);
  return *reinterpret_cast<u16*>(&h);
}

__device__ __forceinline__ void gll16(const void* g, void* l) {
  __builtin_amdgcn_global_load_lds((const __attribute__((address_space(1))) void*)g,
                                   (__attribute__((address_space(3))) void*)l, 16, 0, 0);
}

// swizzled 16B-unit index within a 256x32 bf16 K-half region (row-pair XOR swizzle)
__device__ __forceinline__ int swz16(int r, int cg) {
  int u = ((r & 1) << 2) | cg;
  return ((r >> 1) << 3) | (u ^ ((r >> 1) & 7));
}

// ---------------- top-k index scan ----------------
__global__ void topk_prep(const void* maskp, const int* __restrict__ posids,
                          const float* __restrict__ scores,
                          int* __restrict__ idx, int* __restrict__ posg,
                          float* __restrict__ scalev) {
  int b = blockIdx.x;
  int tid = threadIdx.x, lane = tid & 63, wv = tid >> 6;
  __shared__ int wsum[4];
  __shared__ int base;
  __shared__ int mode;
  __shared__ int detCnt;
  if (tid == 0) { base = 0; detCnt = 0; }
  __syncthreads();
  {
    const unsigned char* mb = (const unsigned char*)maskp;
    int c = 0;
    for (int s = tid; s < 8192; s += 256) c += (mb[s] != 0);
    atomicAdd(&detCnt, c);
  }
  __syncthreads();
  if (tid == 0) mode = (detCnt == KS) ? 1 : 0;
  __syncthreads();
  const unsigned char* mb = (const unsigned char*)maskp;
  const int* mi = (const int*)maskp;
  for (int s0 = 0; s0 < Ss; s0 += 256) {
    int s = s0 + tid;
    int pred = mode ? (mb[(size_t)b * Ss + s] != 0) : (mi[(size_t)b * Ss + s] != 0);
    unsigned long long bal = __ballot(pred);
    int lp = __popcll(bal & ((1ull << lane) - 1ull));
    int wtot = __popcll(bal);
    if (lane == 0) wsum[wv] = wtot;
    __syncthreads();
    int woff = 0;
    for (int w = 0; w < wv; ++w) woff += wsum[w];
    int tot = wsum[0] + wsum[1] + wsum[2] + wsum[3];
    int p = base + woff + lp;
    if (pred && p < KS) {
      idx[b * KS + p] = s;
      posg[b * KS + p] = posids[(size_t)b * Ss + s];
    }
    __syncthreads();
    if (tid == 0) base += tot;
    __syncthreads();
  }
  if (b == 0 && tid < Bb) scalev[tid] = 0.5f * 1.0f + (scores[tid] - 0.5f) * 1.0f;
}

// ---------------- weight transpose fp32 -> bf16 ----------------
__global__ void transpose_w(const float* __restrict__ in, u16* __restrict__ out, int R, int C) {
  __shared__ float tile[32][33];
  int tx = threadIdx.x, ty = threadIdx.y;
  int c0 = blockIdx.x * 32, r0 = blockIdx.y * 32;
  for (int j = ty; j < 32; j += 8) tile[j][tx] = in[(size_t)(r0 + j) * C + c0 + tx];
  __syncthreads();
  for (int j = ty; j < 32; j += 8) out[(size_t)(c0 + j) * R + r0 + tx] = f2b(tile[tx][j]);
}

// ---------------- RMSNorm ----------------
template <int GATHER>
__global__ __launch_bounds__(256) void rmsnorm_k(const float* __restrict__ src0,
                                                 const int* __restrict__ idx,
                                                 const float* __restrict__ w,
                                                 u16* __restrict__ out) {
  int t = blockIdx.x;
  const float* src;
  if (GATHER) { int b = t >> 10; src = src0 + ((size_t)b * Ss + idx[t]) * Hh; }
  else src = src0 + (size_t)t * Hh;
  int tid = threadIdx.x, lane = tid & 63, wv = tid >> 6;
  float4 x0 = *(const float4*)(src + tid * 8);
  float4 x1 = *(const float4*)(src + tid * 8 + 4);
  float ss = x0.x * x0.x + x0.y * x0.y + x0.z * x0.z + x0.w * x0.w +
             x1.x * x1.x + x1.y * x1.y + x1.z * x1.z + x1.w * x1.w;
  for (int o = 32; o; o >>= 1) ss += __shfl_down(ss, o);
  __shared__ float wred[4];
  if (lane == 0) wred[wv] = ss;
  __syncthreads();
  float tot = wred[0] + wred[1] + wred[2] + wred[3];
  float r = rsqrtf(tot * (1.0f / Hh) + 1e-5f);
  const float* wp = w + tid * 8;
  u16* op = out + (size_t)t * Hh + tid * 8;
  float xs[8] = {x0.x, x0.y, x0.z, x0.w, x1.x, x1.y, x1.z, x1.w};
#pragma unroll
  for (int j = 0; j < 8; ++j) op[j] = f2b(xs[j] * r * wp[j]);
}

// ---------------- 256x256 8-phase bf16 GEMM (T2+T3+T4+T5), B^T input ----------------
// LDS regions (16KB each, 256 rows x 32 cols bf16, row-pair swizzled):
//   A: reg = d*2+kk (0..3)   B: reg = 4+d*2+kk (4..7)
// Phase split per K-tile: (kk, m-half). Stage order per K-tile: B.kk0, A.kk0, B.kk1, A.kk1
// (death order), stage lead = 7 halves, vmcnt(6) at each K-tile end.
template <int EPI>
__global__ __launch_bounds__(512, 2) void gemm256(
    const u16* __restrict__ A, const u16* __restrict__ Bt,
    int N, int Kd, int lda, int gm, int gn,
    u16* __restrict__ Cb,
    const float* __restrict__ hid, const int* __restrict__ idx,
    const float* __restrict__ hs2, const float* __restrict__ scalev,
    float* __restrict__ Cf) {
  __shared__ u16 lds[65536];
  int nwg = gm * gn;
  int bid = blockIdx.x;
  int chunk = nwg >> 3;  // all grids divisible by 8
  int wgid = (bid & 7) * chunk + (bid >> 3);
  int bm = wgid / gn, bn = wgid % gn;
  int m0 = bm * 256, n0 = bn * 256;
  int tid = threadIdx.x, lane = tid & 63, wv = tid >> 6;
  int wm = wv >> 2, wn = wv & 3;
  int NT = Kd >> 6;

  // staging per-thread constants (inverse swizzle on global source, linear LDS dest)
  int P16 = wv * 64 + lane;
  int blk = P16 >> 3, up = P16 & 7;
  int uu = up ^ (blk & 7);
  int r0 = blk * 2 + (uu >> 2), cg0 = uu & 3;
  const u16* srcA = A + (size_t)(m0 + r0) * lda + cg0 * 8;
  const u16* srcB = Bt + (size_t)(n0 + r0) * Kd + cg0 * 8;
  size_t rsA = (size_t)128 * lda, rsB = (size_t)128 * Kd;

  // fragment read bases (swizzled)
  int offA = swz16(wm * 128 + (lane & 15), lane >> 4) * 8;
  int offB = swz16(wn * 64 + (lane & 15), lane >> 4) * 8;

  auto stage = [&](int h) {
    int kt2 = h >> 2, j = h & 3;
    int isA = j & 1;          // j=1,3 -> A ; j=0,2 -> B
    int kk = j >> 1;
    int d = kt2 & 1;
    int reg = (isA ? 0 : 4) + d * 2 + kk;
    const u16* sp = (isA ? srcA : srcB) + kt2 * 64 + kk * 32;
    size_t rs = isA ? rsA : rsB;
    u16* dst = &lds[reg * 8192 + wv * 512];
    gll16(sp, dst);
    gll16(sp + rs, dst + 4096);
  };

  f32x4 acc[8][4] = {};
  B8 aR[4], bR[4];

  // prologue: 7 halves (kt0 complete + 3 of kt1), then wait kt0 landed
  for (int h = 0; h < 7; ++h) stage(h);
  asm volatile("s_waitcnt vmcnt(6)" ::: "memory");
  asm volatile("s_barrier" ::: "memory");

  for (int kt = 0; kt < NT; ++kt) {
    int d = kt & 1;
    int s0 = kt * 4;
#pragma unroll
    for (int ph = 0; ph < 4; ++ph) {
      const int kk = ph >> 1, mh = ph & 1;
      if (mh == 0) {
#pragma unroll
        for (int nf = 0; nf < 4; ++nf)
          bR[nf].u = *(const uint4*)&lds[(4 + d * 2 + kk) * 8192 + offB + nf * 512];
      }
#pragma unroll
      for (int i = 0; i < 4; ++i)
        aR[i].u = *(const uint4*)&lds[(d * 2 + kk) * 8192 + offA + (i + 4 * mh) * 512];
      int h = s0 + ph + 7;
      if (h < 4 * NT) stage(h);
      asm volatile("s_barrier" ::: "memory");
      asm volatile("s_waitcnt lgkmcnt(0)" ::: "memory");
      __builtin_amdgcn_s_setprio(1);
#pragma unroll
      for (int nf = 0; nf < 4; ++nf)
#pragma unroll
        for (int i = 0; i < 4; ++i)
          acc[mh * 4 + i][nf] =
              __builtin_amdgcn_mfma_f32_16x16x32_bf16(aR[i].v, bR[nf].v, acc[mh * 4 + i][nf], 0, 0, 0);
      __builtin_amdgcn_s_setprio(0);
      if (ph == 3) {
        if (kt < NT - 2) asm volatile("s_waitcnt vmcnt(6)" ::: "memory");
        else if (kt == NT - 2) asm volatile("s_waitcnt vmcnt(0)" ::: "memory");
      }
      asm volatile("s_barrier" ::: "memory");
    }
  }

#pragma unroll
  for (int mf = 0; mf < 8; ++mf) {
#pragma unroll
    for (int rr = 0; rr < 4; ++rr) {
      int row = m0 + wm * 128 + mf * 16 + (lane >> 4) * 4 + rr;
#pragma unroll
      for (int nf = 0; nf < 4; ++nf) {
        int col = n0 + wn * 64 + nf * 16 + (lane & 15);
        float v = acc[mf][nf][rr];
        if (EPI == 0) {
          Cb[(size_t)row * N + col] = f2b(v);
        } else if (EPI == 1) {
          int b = row >> 10;
          Cf[(size_t)row * Hh + col] = hid[((size_t)b * Ss + idx[row]) * Hh + col] + v;
        } else {
          int b = row >> 10;
          Cf[((size_t)b * Ss + idx[row]) * Hh + col] = hs2[(size_t)row * Hh + col] + v * scalev[b];
        }
      }
    }
  }
}

// ---------------- RoPE on fused QKV buffer (stride 6144) ----------------
__global__ __launch_bounds__(256) void rope_qk(u16* __restrict__ qkv,
                                               const int* __restrict__ posg) {
  int gid = blockIdx.x * 256 + threadIdx.x;  // NTOK*NH*64
  int i = gid & 63;
  int h = (gid >> 6) & 15;
  int t = gid >> 10;
  float p = (float)posg[t];
  float inv = exp2f(-(float)i * (13.287712379549449f / 64.0f));
  float ang = p * inv;
  float sv, cv;
  sincosf(ang, &sv, &cv);
  size_t base = (size_t)t * 6144 + h * DHh + i;
  u16* Q = qkv;
  u16* Kq = qkv + 2048;
  float q1 = b2f(Q[base]), q2 = b2f(Q[base + 64]);
  Q[base] = f2b(q1 * cv - q2 * sv);
  Q[base + 64] = f2b(q2 * cv + q1 * sv);
  float k1 = b2f(Kq[base]), k2 = b2f(Kq[base + 64]);
  Kq[base] = f2b(k1 * cv - k2 * sv);
  Kq[base + 64] = f2b(k2 * cv + k1 * sv);
}

// ---------------- flash attention over fused QKV (stride 6144) ----------------
__global__ __launch_bounds__(256) void attn_k(const u16* __restrict__ QKV, u16* __restrict__ O) {
  int qb = blockIdx.x;
  int head = blockIdx.y;
  int b = head >> 4, h = head & 15;
  int tid = threadIdx.x, lane = tid & 63, wv = tid >> 6;
  __shared__ __align__(16) u16 Ksm[32][136];
  __shared__ __align__(16) u16 Vs[128][40];
  __shared__ __align__(16) u16 Ps[4][16][40];
  int q0 = qb * 64 + wv * 16;
  int tokQ = b * KS + q0;
  B8 qf[4];
  const u16* qp = QKV + (size_t)(tokQ + (lane & 15)) * 6144 + h * DHh;
#pragma unroll
  for (int c = 0; c < 4; ++c) qf[c].u = *(const uint4*)(qp + c * 32 + (lane >> 4) * 8);
  float m_run = -1e30f, l_run = 0.0f;
  f32x4 oacc[8] = {};
  int kmax = qb * 64 + 64;
  for (int ks = 0; ks < kmax; ks += 32) {
    __syncthreads();
    for (int s = tid; s < 512; s += 256) {
      int key = s >> 4, d0 = (s & 15) * 8;
      size_t gb = (size_t)(b * KS + ks + key) * 6144 + 2048 + h * DHh + d0;
      uint4 kv = *(const uint4*)(QKV + gb);
      *(uint4*)&Ksm[key][d0] = kv;
      uint4 vv = *(const uint4*)(QKV + gb + 2048);
      u16* vp = (u16*)&vv;
      int kb = key >> 3, ko = key & 7;
#pragma unroll
      for (int j = 0; j < 8; ++j) {
        int d = d0 + j;
        Vs[d][((kb ^ ((d >> 3) & 3)) << 3) | ko] = vp[j];
      }
    }
    __syncthreads();
    f32x4 st[2] = {};
#pragma unroll
    for (int c = 0; c < 4; ++c) {
      B8 k0f, k1f;
      k0f.u = *(const uint4*)&Ksm[lane & 15][c * 32 + (lane >> 4) * 8];
      k1f.u = *(const uint4*)&Ksm[16 + (lane & 15)][c * 32 + (lane >> 4) * 8];
      st[0] = __builtin_amdgcn_mfma_f32_16x16x32_bf16(k0f.v, qf[c].v, st[0], 0, 0, 0);
      st[1] = __builtin_amdgcn_mfma_f32_16x16x32_bf16(k1f.v, qf[c].v, st[1], 0, 0, 0);
    }
    int qi = q0 + (lane & 15);
    float pmax = -INFINITY;
#pragma unroll
    for (int kt = 0; kt < 2; ++kt)
#pragma unroll
      for (int r = 0; r < 4; ++r) {
        int ki = ks + kt * 16 + (lane >> 4) * 4 + r;
        float v = st[kt][r] * 0.088388347648318447f;
        v = (ki <= qi) ? v : -INFINITY;
        st[kt][r] = v;
        pmax = fmaxf(pmax, v);
      }
    pmax = fmaxf(pmax, __shfl_xor(pmax, 16));
    pmax = fmaxf(pmax, __shfl_xor(pmax, 32));
    float m_new = fmaxf(m_run, pmax);
    float alpha = __expf(m_run - m_new);
    float psum = 0.0f;
#pragma unroll
    for (int kt = 0; kt < 2; ++kt)
#pragma unroll
      for (int r = 0; r < 4; ++r) {
        float pv = __expf(st[kt][r] - m_new);
        st[kt][r] = pv;
        psum += pv;
      }
    psum += __shfl_xor(psum, 16);
    psum += __shfl_xor(psum, 32);
    l_run = l_run * alpha + psum;
    m_run = m_new;
#pragma unroll
    for (int kt = 0; kt < 2; ++kt) {
      ushort4 pk;
      pk.x = f2b(st[kt][0]); pk.y = f2b(st[kt][1]);
      pk.z = f2b(st[kt][2]); pk.w = f2b(st[kt][3]);
      *(ushort4*)&Ps[wv][lane & 15][kt * 16 + (lane >> 4) * 4] = pk;
    }
    B8 pf;
    pf.u = *(const uint4*)&Ps[wv][lane & 15][(lane >> 4) * 8];
    float al0 = __shfl(alpha, (lane >> 4) * 4 + 0);
    float al1 = __shfl(alpha, (lane >> 4) * 4 + 1);
    float al2 = __shfl(alpha, (lane >> 4) * 4 + 2);
    float al3 = __shfl(alpha, (lane >> 4) * 4 + 3);
#pragma unroll
    for (int dt = 0; dt < 8; ++dt) {
      oacc[dt][0] *= al0; oacc[dt][1] *= al1;
      oacc[dt][2] *= al2; oacc[dt][3] *= al3;
    }
#pragma unroll
    for (int dt = 0; dt < 8; ++dt) {
      int d = dt * 16 + (lane & 15);
      B8 vf;
      vf.u = *(const uint4*)&Vs[d][(((lane >> 4) ^ ((d >> 3) & 3)) << 3)];
      oacc[dt] = __builtin_amdgcn_mfma_f32_16x16x32_bf16(pf.v, vf.v, oacc[dt], 0, 0, 0);
    }
  }
  float linv = 1.0f / l_run;
  float li[4];
#pragma unroll
  for (int r = 0; r < 4; ++r) li[r] = __shfl(linv, (lane >> 4) * 4 + r);
#pragma unroll
  for (int r = 0; r < 4; ++r) {
    int tok = tokQ + (lane >> 4) * 4 + r;
    u16* op = O + (size_t)tok * Hh + h * DHh;
#pragma unroll
    for (int dt = 0; dt < 8; ++dt) op[dt * 16 + (lane & 15)] = f2b(oacc[dt][r] * li[r]);
  }
}

// ---------------- silu(g)*u on fused gate|up buffer (stride 16384), in place into g half ----------------
__global__ __launch_bounds__(256) void silu_gu(u16* __restrict__ gu) {
  size_t gid = (size_t)blockIdx.x * 256 + threadIdx.x;
  size_t t = gid >> 10;
  int c = (int)(gid & 1023) * 8;
  u16* gp = gu + t * 16384 + c;
  const u16* upp = gp + 8192;
  B8 gv, uv;
  gv.u = *(const uint4*)gp;
  uv.u = *(const uint4*)upp;
#pragma unroll
  for (int j = 0; j < 8; ++j) {
    float x = b2f(gv.s[j]), y = b2f(uv.s[j]);
    gv.s[j] = f2b(x / (1.0f + __expf(-x)) * y);
  }
  *(uint4*)gp = gv.u;
}

extern "C" void kernel_launch(void* const* d_in, const int* in_sizes, int n_in,
                              void* d_out, int out_size, void* d_ws, size_t ws_size,
                              hipStream_t stream) {
  (void)in_sizes; (void)n_in; (void)out_size; (void)ws_size;
  const float* hid = (const float*)d_in[0];
  const int* posids = (const int*)d_in[1];
  const void* mask = d_in[2];
  const float* scores = (const float*)d_in[3];
  const float* Wq = (const float*)d_in[5];
  const float* Wk = (const float*)d_in[6];
  const float* Wv = (const float*)d_in[7];
  const float* Wo = (const float*)d_in[8];
  const float* Wg = (const float*)d_in[9];
  const float* Wu = (const float*)d_in[10];
  const float* Wd = (const float*)d_in[11];
  const float* ln1 = (const float*)d_in[12];
  const float* ln2 = (const float*)d_in[13];
  float* out = (float*)d_out;
  char* ws = (char*)d_ws;

  u16* WqkvT = (u16*)(ws + 0);            // [6144][2048] bf16 = 25165824 B
  u16* WoT   = (u16*)(ws + 25165824);     // [2048][2048] = 8388608
  u16* WguT  = (u16*)(ws + 33554432);     // [16384][2048] = 67108864
  u16* WdT   = (u16*)(ws + 100663296);    // [2048][8192] = 33554432
  int* idx   = (int*)(ws + 134217728);
  int* posg  = (int*)(ws + 134217728 + 16384);
  float* scalev = (float*)(ws + 134217728 + 32768);
  char* R = ws + 134283264;               // 128MiB pool
  u16* hsn    = (u16*)(R);                // [4096][2048]
  u16* qkv    = (u16*)(R + 16777216);     // [4096][6144]
  u16* attn_o = (u16*)(R + 67108864);     // [4096][2048]
  u16* gu     = (u16*)(R);                // [4096][16384] overlays hsn/qkv/attn_o (dead)
  float* hs2  = (float*)(ws + 268500992); // [4096][2048] f32
  u16* mnorm  = (u16*)(ws + 302055424);   // [4096][2048]

  hipMemcpyAsync(out, hid, (size_t)Bb * Ss * Hh * 4, hipMemcpyDeviceToDevice, stream);

  topk_prep<<<Bb, 256, 0, stream>>>(mask, posids, scores, idx, posg, scalev);

  transpose_w<<<dim3(64, 64), dim3(32, 8), 0, stream>>>(Wq, WqkvT, 2048, 2048);
  transpose_w<<<dim3(64, 64), dim3(32, 8), 0, stream>>>(Wk, WqkvT + 2048 * 2048, 2048, 2048);
  transpose_w<<<dim3(64, 64), dim3(32, 8), 0, stream>>>(Wv, WqkvT + 4096 * 2048, 2048, 2048);
  transpose_w<<<dim3(64, 64), dim3(32, 8), 0, stream>>>(Wo, WoT, 2048, 2048);
  transpose_w<<<dim3(256, 64), dim3(32, 8), 0, stream>>>(Wg, WguT, 2048, 8192);
  transpose_w<<<dim3(256, 64), dim3(32, 8), 0, stream>>>(Wu, WguT + 8192 * 2048, 2048, 8192);
  transpose_w<<<dim3(64, 256), dim3(32, 8), 0, stream>>>(Wd, WdT, 8192, 2048);

  rmsnorm_k<1><<<NTOK, 256, 0, stream>>>(hid, idx, ln1, hsn);

  // QKV fused: [4096,2048] x [2048,6144] -> qkv [4096][6144]
  gemm256<0><<<16 * 24, 512, 0, stream>>>(hsn, WqkvT, 6144, 2048, 2048, 16, 24, qkv,
                                          nullptr, nullptr, nullptr, nullptr, nullptr);

  rope_qk<<<16384, 256, 0, stream>>>(qkv, posg);

  attn_k<<<dim3(16, 64), 256, 0, stream>>>(qkv, attn_o);

  // Wo: attn_o x WoT -> hs2 = gathered residual + o@Wo
  gemm256<1><<<16 * 8, 512, 0, stream>>>(attn_o, WoT, 2048, 2048, 2048, 16, 8, nullptr,
                                         hid, idx, nullptr, nullptr, hs2);

  rmsnorm_k<0><<<NTOK, 256, 0, stream>>>(hs2, nullptr, ln2, mnorm);

  // gate|up fused: mnorm x WguT -> gu [4096][16384]
  gemm256<0><<<16 * 64, 512, 0, stream>>>(mnorm, WguT, 16384, 2048, 2048, 16, 64, gu,
                                          nullptr, nullptr, nullptr, nullptr, nullptr);

  silu_gu<<<16384, 256, 0, stream>>>(gu);

  // down: gu(g half, lda=16384) x WdT -> out (scatter + residual + scale)
  gemm256<2><<<16 * 8, 512, 0, stream>>>(gu, WdT, 2048, 8192, 16384, 16, 8, nullptr,
                                         nullptr, idx, hs2, scalev, out);
}

// Round 3
// 1229.713 us; speedup vs baseline: 1.0633x; 1.0427x over previous
//
#include <hip/hip_runtime.h>
#include <hip/hip_bf16.h>
#include <stdint.h>

#define Bb 4
#define Ss 8192
#define Hh 2048
#define NHh 16
#define DHh 128
#define DFFf 8192
#define KS 1024
#define NTOK 4096

typedef unsigned short u16;
typedef __bf16 bf16x8 __attribute__((ext_vector_type(8)));
typedef float f32x4 __attribute__((ext_vector_type(4)));

union B8 { uint4 u; bf16x8 v; u16 s[8]; };

__device__ __forceinline__ float b2f(u16 x) { return __uint_as_float(((unsigned)x) << 16); }
__device__ __forceinline__ u16 f2b(float x) {
  __hip_bfloat16 h = __float2bfloat16(x);
  return *reinterpret_cast<u16*>(&h);
}

__device__ __forceinline__ void gll16(const void* g, void* l) {
  __builtin_amdgcn_global_load_lds((const __attribute__((address_space(1))) void*)g,
                                   (__attribute__((address_space(3))) void*)l, 16, 0, 0);
}

// swizzled 16B-unit index within a Rx32 bf16 region (row-pair XOR swizzle)
__device__ __forceinline__ int swz16(int r, int cg) {
  int u = ((r & 1) << 2) | cg;
  return ((r >> 1) << 3) | (u ^ ((r >> 1) & 7));
}

// ---------------- top-k index scan ----------------
__global__ void topk_prep(const void* maskp, const int* __restrict__ posids,
                          const float* __restrict__ scores,
                          int* __restrict__ idx, int* __restrict__ posg,
                          float* __restrict__ scalev) {
  int b = blockIdx.x;
  int tid = threadIdx.x, lane = tid & 63, wv = tid >> 6;
  __shared__ int wsum[4];
  __shared__ int base;
  __shared__ int mode;
  __shared__ int detCnt;
  if (tid == 0) { base = 0; detCnt = 0; }
  __syncthreads();
  {
    const unsigned char* mb = (const unsigned char*)maskp;
    int c = 0;
    for (int s = tid; s < 8192; s += 256) c += (mb[s] != 0);
    atomicAdd(&detCnt, c);
  }
  __syncthreads();
  if (tid == 0) mode = (detCnt == KS) ? 1 : 0;
  __syncthreads();
  const unsigned char* mb = (const unsigned char*)maskp;
  const int* mi = (const int*)maskp;
  for (int s0 = 0; s0 < Ss; s0 += 256) {
    int s = s0 + tid;
    int pred = mode ? (mb[(size_t)b * Ss + s] != 0) : (mi[(size_t)b * Ss + s] != 0);
    unsigned long long bal = __ballot(pred);
    int lp = __popcll(bal & ((1ull << lane) - 1ull));
    int wtot = __popcll(bal);
    if (lane == 0) wsum[wv] = wtot;
    __syncthreads();
    int woff = 0;
    for (int w = 0; w < wv; ++w) woff += wsum[w];
    int tot = wsum[0] + wsum[1] + wsum[2] + wsum[3];
    int p = base + woff + lp;
    if (pred && p < KS) {
      idx[b * KS + p] = s;
      posg[b * KS + p] = posids[(size_t)b * Ss + s];
    }
    __syncthreads();
    if (tid == 0) base += tot;
    __syncthreads();
  }
  if (b == 0 && tid < Bb) scalev[tid] = 0.5f * 1.0f + (scores[tid] - 0.5f) * 1.0f;
}

// ---------------- weight transpose fp32 -> bf16 ----------------
__global__ void transpose_w(const float* __restrict__ in, u16* __restrict__ out, int R, int C) {
  __shared__ float tile[32][33];
  int tx = threadIdx.x, ty = threadIdx.y;
  int c0 = blockIdx.x * 32, r0 = blockIdx.y * 32;
  for (int j = ty; j < 32; j += 8) tile[j][tx] = in[(size_t)(r0 + j) * C + c0 + tx];
  __syncthreads();
  for (int j = ty; j < 32; j += 8) out[(size_t)(c0 + j) * R + r0 + tx] = f2b(tile[tx][j]);
}

// ---------------- RMSNorm ----------------
template <int GATHER>
__global__ __launch_bounds__(256) void rmsnorm_k(const float* __restrict__ src0,
                                                 const int* __restrict__ idx,
                                                 const float* __restrict__ w,
                                                 u16* __restrict__ out) {
  int t = blockIdx.x;
  const float* src;
  if (GATHER) { int b = t >> 10; src = src0 + ((size_t)b * Ss + idx[t]) * Hh; }
  else src = src0 + (size_t)t * Hh;
  int tid = threadIdx.x, lane = tid & 63, wv = tid >> 6;
  float4 x0 = *(const float4*)(src + tid * 8);
  float4 x1 = *(const float4*)(src + tid * 8 + 4);
  float ss = x0.x * x0.x + x0.y * x0.y + x0.z * x0.z + x0.w * x0.w +
             x1.x * x1.x + x1.y * x1.y + x1.z * x1.z + x1.w * x1.w;
  for (int o = 32; o; o >>= 1) ss += __shfl_down(ss, o);
  __shared__ float wred[4];
  if (lane == 0) wred[wv] = ss;
  __syncthreads();
  float tot = wred[0] + wred[1] + wred[2] + wred[3];
  float r = rsqrtf(tot * (1.0f / Hh) + 1e-5f);
  const float* wp = w + tid * 8;
  u16* op = out + (size_t)t * Hh + tid * 8;
  float xs[8] = {x0.x, x0.y, x0.z, x0.w, x1.x, x1.y, x1.z, x1.w};
#pragma unroll
  for (int j = 0; j < 8; ++j) op[j] = f2b(xs[j] * r * wp[j]);
}

// ---------------- 256x256 8-phase bf16 GEMM (T1+T2+T3+T4+T5), B^T input ----------------
// Grouped raster: XCD x owns a gm x gw column strip, bm fastest.
template <int EPI>
__global__ __launch_bounds__(512, 2) void gemm256(
    const u16* __restrict__ A, const u16* __restrict__ Bt,
    int N, int Kd, int lda, int gm, int gw,
    u16* __restrict__ Cb,
    const float* __restrict__ hid, const int* __restrict__ idx,
    const float* __restrict__ hs2, const float* __restrict__ scalev,
    float* __restrict__ Cf) {
  __shared__ u16 lds[65536];
  int bid = blockIdx.x;
  int xcd = bid & 7;
  int i = bid >> 3;
  int bm = i % gm;
  int bn = xcd * gw + i / gm;
  int m0 = bm * 256, n0 = bn * 256;
  int tid = threadIdx.x, lane = tid & 63, wv = tid >> 6;
  int wm = wv >> 2, wn = wv & 3;
  int NT = Kd >> 6;

  int P16 = wv * 64 + lane;
  int blk = P16 >> 3, up = P16 & 7;
  int uu = up ^ (blk & 7);
  int r0 = blk * 2 + (uu >> 2), cg0 = uu & 3;
  const u16* srcA = A + (size_t)(m0 + r0) * lda + cg0 * 8;
  const u16* srcB = Bt + (size_t)(n0 + r0) * Kd + cg0 * 8;
  size_t rsA = (size_t)128 * lda, rsB = (size_t)128 * Kd;

  int offA = swz16(wm * 128 + (lane & 15), lane >> 4) * 8;
  int offB = swz16(wn * 64 + (lane & 15), lane >> 4) * 8;

  auto stage = [&](int h) {
    int kt2 = h >> 2, j = h & 3;
    int isA = j & 1;
    int kk = j >> 1;
    int d = kt2 & 1;
    int reg = (isA ? 0 : 4) + d * 2 + kk;
    const u16* sp = (isA ? srcA : srcB) + kt2 * 64 + kk * 32;
    size_t rs = isA ? rsA : rsB;
    u16* dst = &lds[reg * 8192 + wv * 512];
    gll16(sp, dst);
    gll16(sp + rs, dst + 4096);
  };

  f32x4 acc[8][4] = {};
  B8 aR[4], bR[4];

  for (int h = 0; h < 7; ++h) stage(h);
  asm volatile("s_waitcnt vmcnt(6)" ::: "memory");
  asm volatile("s_barrier" ::: "memory");

  for (int kt = 0; kt < NT; ++kt) {
    int d = kt & 1;
    int s0 = kt * 4;
#pragma unroll
    for (int ph = 0; ph < 4; ++ph) {
      const int kk = ph >> 1, mh = ph & 1;
      if (mh == 0) {
#pragma unroll
        for (int nf = 0; nf < 4; ++nf)
          bR[nf].u = *(const uint4*)&lds[(4 + d * 2 + kk) * 8192 + offB + nf * 512];
      }
#pragma unroll
      for (int i2 = 0; i2 < 4; ++i2)
        aR[i2].u = *(const uint4*)&lds[(d * 2 + kk) * 8192 + offA + (i2 + 4 * mh) * 512];
      int h = s0 + ph + 7;
      if (h < 4 * NT) stage(h);
      asm volatile("s_barrier" ::: "memory");
      asm volatile("s_waitcnt lgkmcnt(0)" ::: "memory");
      __builtin_amdgcn_s_setprio(1);
#pragma unroll
      for (int nf = 0; nf < 4; ++nf)
#pragma unroll
        for (int i2 = 0; i2 < 4; ++i2)
          acc[mh * 4 + i2][nf] =
              __builtin_amdgcn_mfma_f32_16x16x32_bf16(aR[i2].v, bR[nf].v, acc[mh * 4 + i2][nf], 0, 0, 0);
      __builtin_amdgcn_s_setprio(0);
      if (ph == 3) {
        if (kt < NT - 2) asm volatile("s_waitcnt vmcnt(6)" ::: "memory");
        else if (kt == NT - 2) asm volatile("s_waitcnt vmcnt(0)" ::: "memory");
      }
      asm volatile("s_barrier" ::: "memory");
    }
  }

#pragma unroll
  for (int mf = 0; mf < 8; ++mf) {
#pragma unroll
    for (int rr = 0; rr < 4; ++rr) {
      int row = m0 + wm * 128 + mf * 16 + (lane >> 4) * 4 + rr;
#pragma unroll
      for (int nf = 0; nf < 4; ++nf) {
        int col = n0 + wn * 64 + nf * 16 + (lane & 15);
        float v = acc[mf][nf][rr];
        if (EPI == 0) {
          Cb[(size_t)row * N + col] = f2b(v);
        } else if (EPI == 1) {
          int b = row >> 10;
          Cf[(size_t)row * Hh + col] = hid[((size_t)b * Ss + idx[row]) * Hh + col] + v;
        } else {
          int b = row >> 10;
          Cf[((size_t)b * Ss + idx[row]) * Hh + col] = hs2[(size_t)row * Hh + col] + v * scalev[b];
        }
      }
    }
  }
}

// ---------------- 128x256 2-phase-per-K-tile bf16 GEMM, same swizzle/vmcnt discipline ----------------
// LDS 96KB: A regions 4x8KB (128x32), B regions 4x16KB (256x32). 3 loads/thread per phase-stage,
// lead = 3 phases, vmcnt(6)/(3)/(0) tail. 8 waves = 2wm x 4wn, wave tile 64x64, 16 MFMA/phase.
template <int EPI>
__global__ __launch_bounds__(512, 2) void gemm128(
    const u16* __restrict__ A, const u16* __restrict__ Bt,
    int N, int Kd, int lda, int gm, int gw,
    u16* __restrict__ Cb,
    const float* __restrict__ hid, const int* __restrict__ idx,
    const float* __restrict__ hs2, const float* __restrict__ scalev,
    float* __restrict__ Cf) {
  __shared__ u16 lds[49152];
  int bid = blockIdx.x;
  int xcd = bid & 7;
  int i = bid >> 3;
  int bm = i % gm;
  int bn = xcd * gw + i / gm;
  int m0 = bm * 128, n0 = bn * 256;
  int tid = threadIdx.x, lane = tid & 63, wv = tid >> 6;
  int wm = wv >> 2, wn = wv & 3;
  int NT = Kd >> 6;
  int P = NT * 2;

  int P16 = wv * 64 + lane;
  int blk = P16 >> 3, up = P16 & 7;
  int uu = up ^ (blk & 7);
  int r0 = blk * 2 + (uu >> 2), cg0 = uu & 3;
  const u16* srcA = A + (size_t)(m0 + r0) * lda + cg0 * 8;  // r0 in [0,128)
  const u16* srcB = Bt + (size_t)(n0 + r0) * Kd + cg0 * 8;
  size_t rsB = (size_t)128 * Kd;

  int offAr[4], offBr[4];
#pragma unroll
  for (int f = 0; f < 4; ++f) {
    offAr[f] = swz16(wm * 64 + f * 16 + (lane & 15), lane >> 4) * 8;
    offBr[f] = swz16(wn * 64 + f * 16 + (lane & 15), lane >> 4) * 8;
  }

  auto stage = [&](int q) {
    int kt = q >> 1, kk = q & 1;
    int slot = ((kt & 1) << 1) | kk;
    const u16* spB = srcB + kt * 64 + kk * 32;
    u16* dstB = &lds[16384 + slot * 8192 + wv * 512];
    gll16(spB, dstB);
    gll16(spB + rsB, dstB + 4096);
    const u16* spA = srcA + kt * 64 + kk * 32;
    gll16(spA, &lds[slot * 4096 + wv * 512]);
  };

  f32x4 acc[4][4] = {};
  B8 aR[4], bR[4];

  stage(0); stage(1); stage(2);
  asm volatile("s_waitcnt vmcnt(6)" ::: "memory");
  asm volatile("s_barrier" ::: "memory");

  for (int p = 0; p < P; ++p) {
    int kt = p >> 1, kk = p & 1;
    int slot = ((kt & 1) << 1) | kk;
    int baseA = slot * 4096;
    int baseB = 16384 + slot * 8192;
#pragma unroll
    for (int f = 0; f < 4; ++f) aR[f].u = *(const uint4*)&lds[baseA + offAr[f]];
#pragma unroll
    for (int f = 0; f < 4; ++f) bR[f].u = *(const uint4*)&lds[baseB + offBr[f]];
    int q = p + 3;
    if (q < P) stage(q);
    asm volatile("s_barrier" ::: "memory");
    asm volatile("s_waitcnt lgkmcnt(0)" ::: "memory");
    __builtin_amdgcn_s_setprio(1);
#pragma unroll
    for (int nf = 0; nf < 4; ++nf)
#pragma unroll
      for (int mf = 0; mf < 4; ++mf)
        acc[mf][nf] = __builtin_amdgcn_mfma_f32_16x16x32_bf16(aR[mf].v, bR[nf].v, acc[mf][nf], 0, 0, 0);
    __builtin_amdgcn_s_setprio(0);
    if (p < P - 3) asm volatile("s_waitcnt vmcnt(6)" ::: "memory");
    else if (p == P - 3) asm volatile("s_waitcnt vmcnt(3)" ::: "memory");
    else if (p == P - 2) asm volatile("s_waitcnt vmcnt(0)" ::: "memory");
    asm volatile("s_barrier" ::: "memory");
  }

#pragma unroll
  for (int mf = 0; mf < 4; ++mf) {
#pragma unroll
    for (int rr = 0; rr < 4; ++rr) {
      int row = m0 + wm * 64 + mf * 16 + (lane >> 4) * 4 + rr;
#pragma unroll
      for (int nf = 0; nf < 4; ++nf) {
        int col = n0 + wn * 64 + nf * 16 + (lane & 15);
        float v = acc[mf][nf][rr];
        if (EPI == 0) {
          Cb[(size_t)row * N + col] = f2b(v);
        } else if (EPI == 1) {
          int b = row >> 10;
          Cf[(size_t)row * Hh + col] = hid[((size_t)b * Ss + idx[row]) * Hh + col] + v;
        } else {
          int b = row >> 10;
          Cf[((size_t)b * Ss + idx[row]) * Hh + col] = hs2[(size_t)row * Hh + col] + v * scalev[b];
        }
      }
    }
  }
}

// ---------------- RoPE on fused QKV buffer (stride 6144) ----------------
__global__ __launch_bounds__(256) void rope_qk(u16* __restrict__ qkv,
                                               const int* __restrict__ posg) {
  int gid = blockIdx.x * 256 + threadIdx.x;
  int i = gid & 63;
  int h = (gid >> 6) & 15;
  int t = gid >> 10;
  float p = (float)posg[t];
  float inv = exp2f(-(float)i * (13.287712379549449f / 64.0f));
  float ang = p * inv;
  float sv, cv;
  sincosf(ang, &sv, &cv);
  size_t base = (size_t)t * 6144 + h * DHh + i;
  u16* Q = qkv;
  u16* Kq = qkv + 2048;
  float q1 = b2f(Q[base]), q2 = b2f(Q[base + 64]);
  Q[base] = f2b(q1 * cv - q2 * sv);
  Q[base + 64] = f2b(q2 * cv + q1 * sv);
  float k1 = b2f(Kq[base]), k2 = b2f(Kq[base + 64]);
  Kq[base] = f2b(k1 * cv - k2 * sv);
  Kq[base + 64] = f2b(k2 * cv + k1 * sv);
}

// ---------------- flash attention over fused QKV (stride 6144) ----------------
__global__ __launch_bounds__(256) void attn_k(const u16* __restrict__ QKV, u16* __restrict__ O) {
  int qb = blockIdx.x;
  int head = blockIdx.y;
  int b = head >> 4, h = head & 15;
  int tid = threadIdx.x, lane = tid & 63, wv = tid >> 6;
  __shared__ __align__(16) u16 Ksm[32][136];
  __shared__ __align__(16) u16 Vs[128][40];
  __shared__ __align__(16) u16 Ps[4][16][40];
  int q0 = qb * 64 + wv * 16;
  int tokQ = b * KS + q0;
  B8 qf[4];
  const u16* qp = QKV + (size_t)(tokQ + (lane & 15)) * 6144 + h * DHh;
#pragma unroll
  for (int c = 0; c < 4; ++c) qf[c].u = *(const uint4*)(qp + c * 32 + (lane >> 4) * 8);
  float m_run = -1e30f, l_run = 0.0f;
  f32x4 oacc[8] = {};
  int kmax = qb * 64 + 64;
  for (int ks = 0; ks < kmax; ks += 32) {
    __syncthreads();
    for (int s = tid; s < 512; s += 256) {
      int key = s >> 4, d0 = (s & 15) * 8;
      size_t gb = (size_t)(b * KS + ks + key) * 6144 + 2048 + h * DHh + d0;
      uint4 kv = *(const uint4*)(QKV + gb);
      *(uint4*)&Ksm[key][d0] = kv;
      uint4 vv = *(const uint4*)(QKV + gb + 2048);
      u16* vp = (u16*)&vv;
      int kb = key >> 3, ko = key & 7;
#pragma unroll
      for (int j = 0; j < 8; ++j) {
        int d = d0 + j;
        Vs[d][((kb ^ ((d >> 3) & 3)) << 3) | ko] = vp[j];
      }
    }
    __syncthreads();
    f32x4 st[2] = {};
#pragma unroll
    for (int c = 0; c < 4; ++c) {
      B8 k0f, k1f;
      k0f.u = *(const uint4*)&Ksm[lane & 15][c * 32 + (lane >> 4) * 8];
      k1f.u = *(const uint4*)&Ksm[16 + (lane & 15)][c * 32 + (lane >> 4) * 8];
      st[0] = __builtin_amdgcn_mfma_f32_16x16x32_bf16(k0f.v, qf[c].v, st[0], 0, 0, 0);
      st[1] = __builtin_amdgcn_mfma_f32_16x16x32_bf16(k1f.v, qf[c].v, st[1], 0, 0, 0);
    }
    int qi = q0 + (lane & 15);
    float pmax = -INFINITY;
#pragma unroll
    for (int kt = 0; kt < 2; ++kt)
#pragma unroll
      for (int r = 0; r < 4; ++r) {
        int ki = ks + kt * 16 + (lane >> 4) * 4 + r;
        float v = st[kt][r] * 0.088388347648318447f;
        v = (ki <= qi) ? v : -INFINITY;
        st[kt][r] = v;
        pmax = fmaxf(pmax, v);
      }
    pmax = fmaxf(pmax, __shfl_xor(pmax, 16));
    pmax = fmaxf(pmax, __shfl_xor(pmax, 32));
    float m_new = fmaxf(m_run, pmax);
    float alpha = __expf(m_run - m_new);
    float psum = 0.0f;
#pragma unroll
    for (int kt = 0; kt < 2; ++kt)
#pragma unroll
      for (int r = 0; r < 4; ++r) {
        float pv = __expf(st[kt][r] - m_new);
        st[kt][r] = pv;
        psum += pv;
      }
    psum += __shfl_xor(psum, 16);
    psum += __shfl_xor(psum, 32);
    l_run = l_run * alpha + psum;
    m_run = m_new;
#pragma unroll
    for (int kt = 0; kt < 2; ++kt) {
      ushort4 pk;
      pk.x = f2b(st[kt][0]); pk.y = f2b(st[kt][1]);
      pk.z = f2b(st[kt][2]); pk.w = f2b(st[kt][3]);
      *(ushort4*)&Ps[wv][lane & 15][kt * 16 + (lane >> 4) * 4] = pk;
    }
    B8 pf;
    pf.u = *(const uint4*)&Ps[wv][lane & 15][(lane >> 4) * 8];
    float al0 = __shfl(alpha, (lane >> 4) * 4 + 0);
    float al1 = __shfl(alpha, (lane >> 4) * 4 + 1);
    float al2 = __shfl(alpha, (lane >> 4) * 4 + 2);
    float al3 = __shfl(alpha, (lane >> 4) * 4 + 3);
#pragma unroll
    for (int dt = 0; dt < 8; ++dt) {
      oacc[dt][0] *= al0; oacc[dt][1] *= al1;
      oacc[dt][2] *= al2; oacc[dt][3] *= al3;
    }
#pragma unroll
    for (int dt = 0; dt < 8; ++dt) {
      int d = dt * 16 + (lane & 15);
      B8 vf;
      vf.u = *(const uint4*)&Vs[d][(((lane >> 4) ^ ((d >> 3) & 3)) << 3)];
      oacc[dt] = __builtin_amdgcn_mfma_f32_16x16x32_bf16(pf.v, vf.v, oacc[dt], 0, 0, 0);
    }
  }
  float linv = 1.0f / l_run;
  float li[4];
#pragma unroll
  for (int r = 0; r < 4; ++r) li[r] = __shfl(linv, (lane >> 4) * 4 + r);
#pragma unroll
  for (int r = 0; r < 4; ++r) {
    int tok = tokQ + (lane >> 4) * 4 + r;
    u16* op = O + (size_t)tok * Hh + h * DHh;
#pragma unroll
    for (int dt = 0; dt < 8; ++dt) op[dt * 16 + (lane & 15)] = f2b(oacc[dt][r] * li[r]);
  }
}

// ---------------- silu(g)*u on fused gate|up buffer (stride 16384), in place into g half ----------------
__global__ __launch_bounds__(256) void silu_gu(u16* __restrict__ gu) {
  size_t gid = (size_t)blockIdx.x * 256 + threadIdx.x;
  size_t t = gid >> 10;
  int c = (int)(gid & 1023) * 8;
  u16* gp = gu + t * 16384 + c;
  const u16* upp = gp + 8192;
  B8 gv, uv;
  gv.u = *(const uint4*)gp;
  uv.u = *(const uint4*)upp;
#pragma unroll
  for (int j = 0; j < 8; ++j) {
    float x = b2f(gv.s[j]), y = b2f(uv.s[j]);
    gv.s[j] = f2b(x / (1.0f + __expf(-x)) * y);
  }
  *(uint4*)gp = gv.u;
}

extern "C" void kernel_launch(void* const* d_in, const int* in_sizes, int n_in,
                              void* d_out, int out_size, void* d_ws, size_t ws_size,
                              hipStream_t stream) {
  (void)in_sizes; (void)n_in; (void)out_size; (void)ws_size;
  const float* hid = (const float*)d_in[0];
  const int* posids = (const int*)d_in[1];
  const void* mask = d_in[2];
  const float* scores = (const float*)d_in[3];
  const float* Wq = (const float*)d_in[5];
  const float* Wk = (const float*)d_in[6];
  const float* Wv = (const float*)d_in[7];
  const float* Wo = (const float*)d_in[8];
  const float* Wg = (const float*)d_in[9];
  const float* Wu = (const float*)d_in[10];
  const float* Wd = (const float*)d_in[11];
  const float* ln1 = (const float*)d_in[12];
  const float* ln2 = (const float*)d_in[13];
  float* out = (float*)d_out;
  char* ws = (char*)d_ws;

  u16* WqkvT = (u16*)(ws + 0);            // [6144][2048] bf16
  u16* WoT   = (u16*)(ws + 25165824);     // [2048][2048]
  u16* WguT  = (u16*)(ws + 33554432);     // [16384][2048]
  u16* WdT   = (u16*)(ws + 100663296);    // [2048][8192]
  int* idx   = (int*)(ws + 134217728);
  int* posg  = (int*)(ws + 134217728 + 16384);
  float* scalev = (float*)(ws + 134217728 + 32768);
  char* R = ws + 134283264;               // 128MiB pool
  u16* hsn    = (u16*)(R);                // [4096][2048]
  u16* qkv    = (u16*)(R + 16777216);     // [4096][6144]
  u16* attn_o = (u16*)(R + 67108864);     // [4096][2048]
  u16* gu     = (u16*)(R);                // [4096][16384] overlays (dead by then)
  float* hs2  = (float*)(ws + 268500992); // [4096][2048] f32
  u16* mnorm  = (u16*)(ws + 302055424);   // [4096][2048]

  hipMemcpyAsync(out, hid, (size_t)Bb * Ss * Hh * 4, hipMemcpyDeviceToDevice, stream);

  topk_prep<<<Bb, 256, 0, stream>>>(mask, posids, scores, idx, posg, scalev);

  transpose_w<<<dim3(64, 64), dim3(32, 8), 0, stream>>>(Wq, WqkvT, 2048, 2048);
  transpose_w<<<dim3(64, 64), dim3(32, 8), 0, stream>>>(Wk, WqkvT + 2048 * 2048, 2048, 2048);
  transpose_w<<<dim3(64, 64), dim3(32, 8), 0, stream>>>(Wv, WqkvT + 4096 * 2048, 2048, 2048);
  transpose_w<<<dim3(64, 64), dim3(32, 8), 0, stream>>>(Wo, WoT, 2048, 2048);
  transpose_w<<<dim3(256, 64), dim3(32, 8), 0, stream>>>(Wg, WguT, 2048, 8192);
  transpose_w<<<dim3(256, 64), dim3(32, 8), 0, stream>>>(Wu, WguT + 8192 * 2048, 2048, 8192);
  transpose_w<<<dim3(64, 256), dim3(32, 8), 0, stream>>>(Wd, WdT, 8192, 2048);

  rmsnorm_k<1><<<NTOK, 256, 0, stream>>>(hid, idx, ln1, hsn);

  // QKV fused: [4096,2048] x [2048,6144] -> qkv   (BM=128: 32x24=768 blocks, gw=3)
  gemm128<0><<<768, 512, 0, stream>>>(hsn, WqkvT, 6144, 2048, 2048, 32, 3, qkv,
                                      nullptr, nullptr, nullptr, nullptr, nullptr);

  rope_qk<<<16384, 256, 0, stream>>>(qkv, posg);

  attn_k<<<dim3(16, 64), 256, 0, stream>>>(qkv, attn_o);

  // Wo: attn_o x WoT -> hs2 (BM=128: 32x8=256 blocks, gw=1)
  gemm128<1><<<256, 512, 0, stream>>>(attn_o, WoT, 2048, 2048, 2048, 32, 1, nullptr,
                                      hid, idx, nullptr, nullptr, hs2);

  rmsnorm_k<0><<<NTOK, 256, 0, stream>>>(hs2, nullptr, ln2, mnorm);

  // gate|up fused: mnorm x WguT -> gu (BM=256: 16x64=1024 blocks, gw=8)
  gemm256<0><<<1024, 512, 0, stream>>>(mnorm, WguT, 16384, 2048, 2048, 16, 8, gu,
                                       nullptr, nullptr, nullptr, nullptr, nullptr);

  silu_gu<<<16384, 256, 0, stream>>>(gu);

  // down: gu(g half, lda=16384) x WdT -> out (BM=128: 32x8=256 blocks, gw=1)
  gemm128<2><<<256, 512, 0, stream>>>(gu, WdT, 2048, 8192, 16384, 32, 1, nullptr,
                                      nullptr, idx, hs2, scalev, out);
}